// Round 1
// baseline (238.810 us; speedup 1.0000x reference)
//
#include <hip/hip_runtime.h>
#include <hip/hip_cooperative_groups.h>

namespace cg = cooperative_groups;

// B=D=H=512. Inputs fp32: x, W1, b1, W2, b2, w3, b3.
// d_out = out[512] ++ gram[512,512] (fp32).
// G = 1 + H2H2^T + (1+H1H1^T)⊙(G2G2^T) + (1+XX^T)⊙(G1G1^T)
//   g2 = w3⊙1{z2>0};  g1 = (W2 g2)⊙1{z1>0}
// Single cooperative kernel, 5 phases separated by grid.sync():
//   P0 prep (splits/transposes)  P1 fwd1  P2 fwd2  P3 g1  P4 gram.
// Same per-phase math as the verified 5-kernel version; fusion removes
// 4 inter-kernel launch gaps (dominant cost: total compute ~16 us vs
// 114.7 us measured).

#define NN 512

typedef __attribute__((ext_vector_type(8))) short v8s;
typedef __attribute__((ext_vector_type(4))) float v4f;

static __device__ __forceinline__ unsigned short f2bf(float f) {
    union { float f; unsigned u; } v; v.f = f;
    unsigned r = v.u + 0x7FFF + ((v.u >> 16) & 1);
    return (unsigned short)(r >> 16);
}
static __device__ __forceinline__ float bf2f(unsigned short h) {
    union { unsigned u; float f; } v; v.u = ((unsigned)h) << 16;
    return v.f;
}

#define MFMA(a, b, c) __builtin_amdgcn_mfma_f32_16x16x32_bf16(a, b, c, 0, 0, 0)

__global__ __launch_bounds__(256, 1) void fused(
    const float* __restrict__ x, const float* __restrict__ W1,
    const float* __restrict__ b1, const float* __restrict__ W2,
    const float* __restrict__ b2, const float* __restrict__ w3,
    const float* __restrict__ b3,
    unsigned short* __restrict__ xhi, unsigned short* __restrict__ xlo,
    unsigned short* __restrict__ W1th, unsigned short* __restrict__ W1tl,
    unsigned short* __restrict__ W2th, unsigned short* __restrict__ W2tl,
    unsigned short* __restrict__ W2b,
    unsigned short* __restrict__ H1b, unsigned short* __restrict__ H1lo,
    unsigned short* __restrict__ H2b, unsigned short* __restrict__ G2b,
    unsigned short* __restrict__ G1b,
    float* __restrict__ out, float* __restrict__ gram) {
    cg::grid_group grid = cg::this_grid();
    const int t = threadIdx.x;
    const int bid = blockIdx.x;
    const int bx = bid & 15, by = bid >> 4;
    const int wave = t >> 6, lane = t & 63;
    const int r = lane & 15, quad = lane >> 4;
    const int i0 = by * 32 + 16 * (wave >> 1);
    const int j0 = bx * 32 + 16 * (wave & 1);
    const int ao = (i0 + r) * NN + quad * 8;
    const int bo = (j0 + r) * NN + quad * 8;

    // ================= P0: prep =================
    {
        __shared__ float T[32][33];
        const int lr = t >> 3, lc = (t & 7) * 4;
        const int r0 = by * 32, c0 = bx * 32;
        // x straight split + out init
        float4 v = *(const float4*)&x[(r0 + lr) * NN + c0 + lc];
        ushort4 hi, lo;
        hi.x = f2bf(v.x); lo.x = f2bf(v.x - bf2f(hi.x));
        hi.y = f2bf(v.y); lo.y = f2bf(v.y - bf2f(hi.y));
        hi.z = f2bf(v.z); lo.z = f2bf(v.z - bf2f(hi.z));
        hi.w = f2bf(v.w); lo.w = f2bf(v.w - bf2f(hi.w));
        *(ushort4*)&xhi[(r0 + lr) * NN + c0 + lc] = hi;
        *(ushort4*)&xlo[(r0 + lr) * NN + c0 + lc] = lo;
        if (bx == 0 && t < 32) out[r0 + t] = b3[0];
        // W1, W2: transpose + split (W2 also stored straight in plain bf16)
        #pragma unroll
        for (int z = 0; z < 2; ++z) {
            const float* src = z ? W2 : W1;
            float4 w = *(const float4*)&src[(r0 + lr) * NN + c0 + lc];
            if (z) {
                ushort4 h;
                h.x = f2bf(w.x); h.y = f2bf(w.y);
                h.z = f2bf(w.z); h.w = f2bf(w.w);
                *(ushort4*)&W2b[(r0 + lr) * NN + c0 + lc] = h;
            }
            T[lr][lc + 0] = w.x; T[lr][lc + 1] = w.y;
            T[lr][lc + 2] = w.z; T[lr][lc + 3] = w.w;
            __syncthreads();
            unsigned short* dh = z ? W2th : W1th;
            unsigned short* dl = z ? W2tl : W1tl;
            float a0 = T[lc + 0][lr], a1 = T[lc + 1][lr];
            float a2 = T[lc + 2][lr], a3 = T[lc + 3][lr];
            ushort4 th, tl;
            th.x = f2bf(a0); tl.x = f2bf(a0 - bf2f(th.x));
            th.y = f2bf(a1); tl.y = f2bf(a1 - bf2f(th.y));
            th.z = f2bf(a2); tl.z = f2bf(a2 - bf2f(th.z));
            th.w = f2bf(a3); tl.w = f2bf(a3 - bf2f(th.w));
            *(ushort4*)&dh[(c0 + lr) * NN + r0 + lc] = th;
            *(ushort4*)&dl[(c0 + lr) * NN + r0 + lc] = tl;
            __syncthreads();
        }
    }
    grid.sync();

    // ================= P1: fwd1 — h1 = relu(x@W1+b1), split output ========
    {
        v4f hh = {0.f, 0.f, 0.f, 0.f}, lh = hh, hl = hh;
        #pragma unroll
        for (int k0 = 0; k0 < NN; k0 += 32) {
            v8s ah = *(const v8s*)(xhi + ao + k0);
            v8s al = *(const v8s*)(xlo + ao + k0);
            v8s bh = *(const v8s*)(W1th + bo + k0);
            v8s bl = *(const v8s*)(W1tl + bo + k0);
            hh = MFMA(ah, bh, hh);
            lh = MFMA(al, bh, lh);
            hl = MFMA(ah, bl, hl);
        }
        const float bj = b1[j0 + r];
        #pragma unroll
        for (int rr = 0; rr < 4; ++rr) {
            const int i = i0 + quad * 4 + rr, j = j0 + r;
            float zv = (hh[rr] + lh[rr]) + hl[rr] + bj;
            float h = zv > 0.f ? zv : 0.f;
            unsigned short hb = f2bf(h);
            H1b[i * NN + j] = hb;
            H1lo[i * NN + j] = f2bf(h - bf2f(hb));
        }
    }
    grid.sync();

    // ================= P2: fwd2 — z2 = h1@W2+b2; H2b, G2b, out += h2.w3 ===
    {
        v4f hh = {0.f, 0.f, 0.f, 0.f}, lh = hh, hl = hh;
        #pragma unroll
        for (int k0 = 0; k0 < NN; k0 += 32) {
            v8s ah = *(const v8s*)(H1b + ao + k0);
            v8s al = *(const v8s*)(H1lo + ao + k0);
            v8s bh = *(const v8s*)(W2th + bo + k0);
            v8s bl = *(const v8s*)(W2tl + bo + k0);
            hh = MFMA(ah, bh, hh);
            lh = MFMA(al, bh, lh);
            hl = MFMA(ah, bl, hl);
        }
        const float bj = b2[j0 + r];
        const float wj = w3[j0 + r];
        const unsigned short wjb = f2bf(wj);
        #pragma unroll
        for (int rr = 0; rr < 4; ++rr) {
            const int i = i0 + quad * 4 + rr, j = j0 + r;
            float zv = (hh[rr] + lh[rr]) + hl[rr] + bj;
            float h = zv > 0.f ? zv : 0.f;
            H2b[i * NN + j] = f2bf(h);
            G2b[i * NN + j] = (zv > 0.f) ? wjb : (unsigned short)0;
            float p = h * wj;
            p += __shfl_xor(p, 1, 64);
            p += __shfl_xor(p, 2, 64);
            p += __shfl_xor(p, 4, 64);
            p += __shfl_xor(p, 8, 64);
            if (r == 0) atomicAdd(&out[i], p);
        }
    }
    grid.sync();

    // ================= P3: g1 — G1 = 1{h1>0} . (G2 @ W2^T) ================
    {
        v4f acc = {0.f, 0.f, 0.f, 0.f};
        #pragma unroll
        for (int k0 = 0; k0 < NN; k0 += 32) {
            v8s a = *(const v8s*)(G2b + ao + k0);
            v8s b = *(const v8s*)(W2b + bo + k0);
            acc = MFMA(a, b, acc);
        }
        #pragma unroll
        for (int rr = 0; rr < 4; ++rr) {
            const int i = i0 + quad * 4 + rr;
            const int c = j0 + r;
            // h >= 0, bf16(h) > 0 iff h > 0 (up to denormal cutoff)
            float v = (H1b[i * NN + c] != 0) ? acc[rr] : 0.f;
            G1b[i * NN + c] = f2bf(v);
        }
    }
    grid.sync();

    // ================= P4: gram — 5 bf16 syrks fused ======================
    {
        v4f a0 = {0.f, 0.f, 0.f, 0.f}, a1 = a0, a2 = a0, a3 = a0, a4 = a0;
        #pragma unroll
        for (int k0 = 0; k0 < NN; k0 += 32) {
            v8s xa = *(const v8s*)(xhi + ao + k0), xb2 = *(const v8s*)(xhi + bo + k0);
            v8s ha = *(const v8s*)(H1b + ao + k0), hb = *(const v8s*)(H1b + bo + k0);
            v8s ga = *(const v8s*)(G1b + ao + k0), gb = *(const v8s*)(G1b + bo + k0);
            v8s ua = *(const v8s*)(H2b + ao + k0), ub = *(const v8s*)(H2b + bo + k0);
            v8s va = *(const v8s*)(G2b + ao + k0), vb = *(const v8s*)(G2b + bo + k0);
            a0 = MFMA(xa, xb2, a0);
            a1 = MFMA(ha, hb, a1);
            a2 = MFMA(ga, gb, a2);
            a3 = MFMA(ua, ub, a3);
            a4 = MFMA(va, vb, a4);
        }
        #pragma unroll
        for (int rr = 0; rr < 4; ++rr) {
            const int i = i0 + quad * 4 + rr;
            const int j = j0 + r;
            float g = 1.f + a3[rr] + a4[rr] * (1.f + a1[rr]) + a2[rr] * (1.f + a0[rr]);
            gram[i * NN + j] = g;
        }
    }
}

extern "C" void kernel_launch(void* const* d_in, const int* in_sizes, int n_in,
                              void* d_out, int out_size, void* d_ws, size_t ws_size,
                              hipStream_t stream) {
    const float* x  = (const float*)d_in[0];
    const float* W1 = (const float*)d_in[1];
    const float* b1 = (const float*)d_in[2];
    const float* W2 = (const float*)d_in[3];
    const float* b2 = (const float*)d_in[4];
    const float* w3 = (const float*)d_in[5];
    const float* b3 = (const float*)d_in[6];

    float* out  = (float*)d_out;
    float* gram = out + NN;

    // 12 bf16 [512][512] arrays, 512 KB each = 6 MB total
    unsigned short* p    = (unsigned short*)d_ws;
    unsigned short* xhi  = p;  p += NN * NN;
    unsigned short* xlo  = p;  p += NN * NN;
    unsigned short* W1th = p;  p += NN * NN;
    unsigned short* W1tl = p;  p += NN * NN;
    unsigned short* W2th = p;  p += NN * NN;
    unsigned short* W2tl = p;  p += NN * NN;
    unsigned short* W2b  = p;  p += NN * NN;
    unsigned short* H1b  = p;  p += NN * NN;
    unsigned short* H1lo = p;  p += NN * NN;
    unsigned short* H2b  = p;  p += NN * NN;
    unsigned short* G2b  = p;  p += NN * NN;
    unsigned short* G1b  = p;  p += NN * NN;

    void* args[] = {
        (void*)&x, (void*)&W1, (void*)&b1, (void*)&W2, (void*)&b2,
        (void*)&w3, (void*)&b3,
        (void*)&xhi, (void*)&xlo, (void*)&W1th, (void*)&W1tl,
        (void*)&W2th, (void*)&W2tl, (void*)&W2b,
        (void*)&H1b, (void*)&H1lo, (void*)&H2b, (void*)&G2b, (void*)&G1b,
        (void*)&out, (void*)&gram,
    };
    hipLaunchCooperativeKernel((const void*)fused, dim3(256), dim3(256),
                               args, 0, stream);
}

// Round 2
// 116.002 us; speedup vs baseline: 2.0587x; 2.0587x over previous
//
#include <hip/hip_runtime.h>

// B=D=H=512. Inputs fp32: x, W1, b1, W2, b2, w3, b3.
// d_out = out[512] ++ gram[512,512] (fp32).
// G = 1 + H2H2^T + (1+H1H1^T)⊙(G2G2^T) + (1+XX^T)⊙(G1G1^T)
//   g2 = w3⊙1{z2>0};  g1 = (W2 g2)⊙1{z1>0}
// 5 plain launches (cooperative fusion regressed: grid.sync flushes L2 on
// non-coherent XCDs -> 25MB HBM @160GB/s latency-bound).
// R2 change: in-block split-K. GEMM phases use 1024-thread blocks
// (16 waves = 4 quadrants x 4 K-slices of 128) + LDS reduction.
// Raises occupancy 1 -> 4 waves/SIMD and cuts each wave's serial K chain
// 16 -> 4 unrolled iterations (all loads hoistable within 128 VGPRs).

#define NN 512

typedef __attribute__((ext_vector_type(8))) short v8s;
typedef __attribute__((ext_vector_type(4))) float v4f;

static __device__ __forceinline__ unsigned short f2bf(float f) {
    union { float f; unsigned u; } v; v.f = f;
    unsigned r = v.u + 0x7FFF + ((v.u >> 16) & 1);
    return (unsigned short)(r >> 16);
}
static __device__ __forceinline__ float bf2f(unsigned short h) {
    union { unsigned u; float f; } v; v.u = ((unsigned)h) << 16;
    return v.f;
}

#define MFMA(a, b, c) __builtin_amdgcn_mfma_f32_16x16x32_bf16(a, b, c, 0, 0, 0)

// ---- prep: z=0: W1 transpose+split; z=1: W2 transpose+split + plain W2b;
//            z=2: x straight split + out[i]=b3 ------------------------------
__global__ __launch_bounds__(256) void prep(
    const float* __restrict__ x, const float* __restrict__ W1,
    const float* __restrict__ W2, const float* __restrict__ b3,
    unsigned short* __restrict__ xhi, unsigned short* __restrict__ xlo,
    unsigned short* __restrict__ W1th, unsigned short* __restrict__ W1tl,
    unsigned short* __restrict__ W2th, unsigned short* __restrict__ W2tl,
    unsigned short* __restrict__ W2b, float* __restrict__ out) {
    __shared__ float T[32][33];
    const int t = threadIdx.x;
    const int lr = t >> 3, lc = (t & 7) * 4;
    const int r0 = blockIdx.y * 32, c0 = blockIdx.x * 32;
    const int z = blockIdx.z;
    if (z == 2) {
        float4 v = *(const float4*)&x[(r0 + lr) * NN + c0 + lc];
        ushort4 hi, lo;
        hi.x = f2bf(v.x); lo.x = f2bf(v.x - bf2f(hi.x));
        hi.y = f2bf(v.y); lo.y = f2bf(v.y - bf2f(hi.y));
        hi.z = f2bf(v.z); lo.z = f2bf(v.z - bf2f(hi.z));
        hi.w = f2bf(v.w); lo.w = f2bf(v.w - bf2f(hi.w));
        *(ushort4*)&xhi[(r0 + lr) * NN + c0 + lc] = hi;
        *(ushort4*)&xlo[(r0 + lr) * NN + c0 + lc] = lo;
        if (blockIdx.x == 0 && t < 32) out[r0 + t] = b3[0];
        return;
    }
    const float* src = (z == 1) ? W2 : W1;
    float4 v = *(const float4*)&src[(r0 + lr) * NN + c0 + lc];
    if (z == 1) {
        ushort4 h;
        h.x = f2bf(v.x); h.y = f2bf(v.y); h.z = f2bf(v.z); h.w = f2bf(v.w);
        *(ushort4*)&W2b[(r0 + lr) * NN + c0 + lc] = h;
    }
    T[lr][lc + 0] = v.x; T[lr][lc + 1] = v.y;
    T[lr][lc + 2] = v.z; T[lr][lc + 3] = v.w;
    __syncthreads();
    unsigned short* dh = (z == 1) ? W2th : W1th;
    unsigned short* dl = (z == 1) ? W2tl : W1tl;
    float a0 = T[lc + 0][lr], a1 = T[lc + 1][lr];
    float a2 = T[lc + 2][lr], a3 = T[lc + 3][lr];
    ushort4 hi, lo;
    hi.x = f2bf(a0); lo.x = f2bf(a0 - bf2f(hi.x));
    hi.y = f2bf(a1); lo.y = f2bf(a1 - bf2f(hi.y));
    hi.z = f2bf(a2); lo.z = f2bf(a2 - bf2f(hi.z));
    hi.w = f2bf(a3); lo.w = f2bf(a3 - bf2f(hi.w));
    *(ushort4*)&dh[(c0 + lr) * NN + r0 + lc] = hi;
    *(ushort4*)&dl[(c0 + lr) * NN + r0 + lc] = lo;
}

// ---- fwd1: h = relu(x@W1+b1) split-bf16; 16 waves = 4 quad x 4 kslice ----
__global__ __launch_bounds__(1024, 4) void fwd1(
    const unsigned short* __restrict__ Ahi, const unsigned short* __restrict__ Alo,
    const unsigned short* __restrict__ Bhi, const unsigned short* __restrict__ Blo,
    const float* __restrict__ bias,
    unsigned short* __restrict__ Chi, unsigned short* __restrict__ Clo) {
    __shared__ float red[12][64][4];
    const int t = threadIdx.x;
    const int wave = t >> 6, lane = t & 63;
    const int q = wave & 3, s = wave >> 2;
    const int r = lane & 15, quad = lane >> 4;
    const int i0 = blockIdx.y * 32 + 16 * (q >> 1);
    const int j0 = blockIdx.x * 32 + 16 * (q & 1);
    const int ao = (i0 + r) * NN + quad * 8 + s * 128;
    const int bo = (j0 + r) * NN + quad * 8 + s * 128;
    v4f hh = {0.f, 0.f, 0.f, 0.f}, lh = hh, hl = hh;
    #pragma unroll
    for (int k0 = 0; k0 < 128; k0 += 32) {
        v8s ah = *(const v8s*)(Ahi + ao + k0);
        v8s al = *(const v8s*)(Alo + ao + k0);
        v8s bh = *(const v8s*)(Bhi + bo + k0);
        v8s bl = *(const v8s*)(Blo + bo + k0);
        hh = MFMA(ah, bh, hh);
        lh = MFMA(al, bh, lh);
        hl = MFMA(ah, bl, hl);
    }
    v4f z;
    #pragma unroll
    for (int rr = 0; rr < 4; ++rr) z[rr] = (hh[rr] + lh[rr]) + hl[rr];
    if (s > 0) *(v4f*)red[(s - 1) * 4 + q][lane] = z;
    __syncthreads();
    if (s == 0) {
        v4f z0 = z + *(v4f*)red[q][lane] + *(v4f*)red[4 + q][lane]
                   + *(v4f*)red[8 + q][lane];
        const float bj = bias[j0 + r];
        #pragma unroll
        for (int rr = 0; rr < 4; ++rr) {
            const int i = i0 + quad * 4 + rr, j = j0 + r;
            float zv = z0[rr] + bj;
            float h = zv > 0.f ? zv : 0.f;
            unsigned short hi = f2bf(h);
            Chi[i * NN + j] = hi;
            Clo[i * NN + j] = f2bf(h - bf2f(hi));
        }
    }
}

// ---- fwd2: z2 = H1@W2+b2; writes H2b, G2b, out += h2.w3 ------------------
__global__ __launch_bounds__(1024, 4) void fwd2(
    const unsigned short* __restrict__ Ahi, const unsigned short* __restrict__ Alo,
    const unsigned short* __restrict__ Bhi, const unsigned short* __restrict__ Blo,
    const float* __restrict__ b2, const float* __restrict__ w3,
    unsigned short* __restrict__ H2b, unsigned short* __restrict__ G2b,
    float* __restrict__ out) {
    __shared__ float red[12][64][4];
    const int t = threadIdx.x;
    const int wave = t >> 6, lane = t & 63;
    const int q = wave & 3, s = wave >> 2;
    const int r = lane & 15, quad = lane >> 4;
    const int i0 = blockIdx.y * 32 + 16 * (q >> 1);
    const int j0 = blockIdx.x * 32 + 16 * (q & 1);
    const int ao = (i0 + r) * NN + quad * 8 + s * 128;
    const int bo = (j0 + r) * NN + quad * 8 + s * 128;
    v4f hh = {0.f, 0.f, 0.f, 0.f}, lh = hh, hl = hh;
    #pragma unroll
    for (int k0 = 0; k0 < 128; k0 += 32) {
        v8s ah = *(const v8s*)(Ahi + ao + k0);
        v8s al = *(const v8s*)(Alo + ao + k0);
        v8s bh = *(const v8s*)(Bhi + bo + k0);
        v8s bl = *(const v8s*)(Blo + bo + k0);
        hh = MFMA(ah, bh, hh);
        lh = MFMA(al, bh, lh);
        hl = MFMA(ah, bl, hl);
    }
    v4f z;
    #pragma unroll
    for (int rr = 0; rr < 4; ++rr) z[rr] = (hh[rr] + lh[rr]) + hl[rr];
    if (s > 0) *(v4f*)red[(s - 1) * 4 + q][lane] = z;
    __syncthreads();
    if (s == 0) {
        v4f z0 = z + *(v4f*)red[q][lane] + *(v4f*)red[4 + q][lane]
                   + *(v4f*)red[8 + q][lane];
        const float bj = b2[j0 + r];
        const float wj = w3[j0 + r];
        const unsigned short wjb = f2bf(wj);
        #pragma unroll
        for (int rr = 0; rr < 4; ++rr) {
            const int i = i0 + quad * 4 + rr, j = j0 + r;
            float zv = z0[rr] + bj;
            float h = zv > 0.f ? zv : 0.f;
            H2b[i * NN + j] = f2bf(h);
            G2b[i * NN + j] = (zv > 0.f) ? wjb : (unsigned short)0;
            float p = h * wj;
            p += __shfl_xor(p, 1, 64);
            p += __shfl_xor(p, 2, 64);
            p += __shfl_xor(p, 4, 64);
            p += __shfl_xor(p, 8, 64);
            if (r == 0) atomicAdd(&out[i], p);
        }
    }
}

// ---- g1: G1b[i,c] = 1{H1>0} * (G2b @ W2^T), bf16 MFMA --------------------
__global__ __launch_bounds__(1024, 4) void g1k(
    const unsigned short* __restrict__ G2b, const unsigned short* __restrict__ W2b,
    const unsigned short* __restrict__ H1b, unsigned short* __restrict__ G1b) {
    __shared__ float red[12][64][4];
    const int t = threadIdx.x;
    const int wave = t >> 6, lane = t & 63;
    const int q = wave & 3, s = wave >> 2;
    const int r = lane & 15, quad = lane >> 4;
    const int i0 = blockIdx.y * 32 + 16 * (q >> 1);
    const int c0 = blockIdx.x * 32 + 16 * (q & 1);
    const unsigned short* arow = G2b + (i0 + r) * NN + quad * 8 + s * 128;
    const unsigned short* brow = W2b + (c0 + r) * NN + quad * 8 + s * 128;
    v4f acc = {0.f, 0.f, 0.f, 0.f};
    #pragma unroll
    for (int k0 = 0; k0 < 128; k0 += 32) {
        v8s a = *(const v8s*)(arow + k0);
        v8s b = *(const v8s*)(brow + k0);
        acc = MFMA(a, b, acc);
    }
    if (s > 0) *(v4f*)red[(s - 1) * 4 + q][lane] = acc;
    __syncthreads();
    if (s == 0) {
        v4f a0 = acc + *(v4f*)red[q][lane] + *(v4f*)red[4 + q][lane]
                     + *(v4f*)red[8 + q][lane];
        #pragma unroll
        for (int rr = 0; rr < 4; ++rr) {
            const int i = i0 + quad * 4 + rr;
            const int c = c0 + r;
            // h >= 0, bf16(h) > 0 iff h > 0 (up to denormal cutoff)
            float v = (H1b[i * NN + c] != 0) ? a0[rr] : 0.f;
            G1b[i * NN + c] = f2bf(v);
        }
    }
}

// ---- gram: 5 bf16 syrks fused, split-K x4 --------------------------------
__global__ __launch_bounds__(1024, 4) void gramk(
    const unsigned short* __restrict__ Xb, const unsigned short* __restrict__ H1b,
    const unsigned short* __restrict__ G1b, const unsigned short* __restrict__ H2b,
    const unsigned short* __restrict__ G2b, float* __restrict__ gram) {
    __shared__ float red[12][64][5][4];
    const int t = threadIdx.x;
    const int wave = t >> 6, lane = t & 63;
    const int q = wave & 3, s = wave >> 2;
    const int r = lane & 15, quad = lane >> 4;
    const int i0 = blockIdx.y * 32 + 16 * (q >> 1);
    const int j0 = blockIdx.x * 32 + 16 * (q & 1);
    const int ao = (i0 + r) * NN + quad * 8 + s * 128;
    const int bo = (j0 + r) * NN + quad * 8 + s * 128;
    v4f a0 = {0.f, 0.f, 0.f, 0.f}, a1 = a0, a2 = a0, a3 = a0, a4 = a0;
    #pragma unroll
    for (int k0 = 0; k0 < 128; k0 += 32) {
        v8s xa = *(const v8s*)(Xb  + ao + k0), xb2 = *(const v8s*)(Xb  + bo + k0);
        v8s ha = *(const v8s*)(H1b + ao + k0), hb  = *(const v8s*)(H1b + bo + k0);
        v8s ga = *(const v8s*)(G1b + ao + k0), gb  = *(const v8s*)(G1b + bo + k0);
        v8s ua = *(const v8s*)(H2b + ao + k0), ub  = *(const v8s*)(H2b + bo + k0);
        v8s va = *(const v8s*)(G2b + ao + k0), vb  = *(const v8s*)(G2b + bo + k0);
        a0 = MFMA(xa, xb2, a0);
        a1 = MFMA(ha, hb,  a1);
        a2 = MFMA(ga, gb,  a2);
        a3 = MFMA(ua, ub,  a3);
        a4 = MFMA(va, vb,  a4);
    }
    if (s > 0) {
        const int idx = (s - 1) * 4 + q;
        *(v4f*)red[idx][lane][0] = a0;
        *(v4f*)red[idx][lane][1] = a1;
        *(v4f*)red[idx][lane][2] = a2;
        *(v4f*)red[idx][lane][3] = a3;
        *(v4f*)red[idx][lane][4] = a4;
    }
    __syncthreads();
    if (s == 0) {
        #pragma unroll
        for (int u = 0; u < 3; ++u) {
            const int idx = u * 4 + q;
            a0 += *(v4f*)red[idx][lane][0];
            a1 += *(v4f*)red[idx][lane][1];
            a2 += *(v4f*)red[idx][lane][2];
            a3 += *(v4f*)red[idx][lane][3];
            a4 += *(v4f*)red[idx][lane][4];
        }
        #pragma unroll
        for (int rr = 0; rr < 4; ++rr) {
            const int i = i0 + quad * 4 + rr;
            const int j = j0 + r;
            float g = 1.f + a3[rr] + a4[rr] * (1.f + a1[rr]) + a2[rr] * (1.f + a0[rr]);
            gram[i * NN + j] = g;
        }
    }
}

extern "C" void kernel_launch(void* const* d_in, const int* in_sizes, int n_in,
                              void* d_out, int out_size, void* d_ws, size_t ws_size,
                              hipStream_t stream) {
    const float* x  = (const float*)d_in[0];
    const float* W1 = (const float*)d_in[1];
    const float* b1 = (const float*)d_in[2];
    const float* W2 = (const float*)d_in[3];
    const float* b2 = (const float*)d_in[4];
    const float* w3 = (const float*)d_in[5];
    const float* b3 = (const float*)d_in[6];

    float* out  = (float*)d_out;
    float* gram = out + NN;

    // 12 bf16 [512][512] arrays, 512 KB each = 6 MB total
    unsigned short* p    = (unsigned short*)d_ws;
    unsigned short* xhi  = p;  p += NN * NN;
    unsigned short* xlo  = p;  p += NN * NN;
    unsigned short* W1th = p;  p += NN * NN;
    unsigned short* W1tl = p;  p += NN * NN;
    unsigned short* W2th = p;  p += NN * NN;
    unsigned short* W2tl = p;  p += NN * NN;
    unsigned short* W2b  = p;  p += NN * NN;
    unsigned short* H1b  = p;  p += NN * NN;
    unsigned short* H1lo = p;  p += NN * NN;
    unsigned short* H2b  = p;  p += NN * NN;
    unsigned short* G2b  = p;  p += NN * NN;
    unsigned short* G1b  = p;  p += NN * NN;

    dim3 blk(256);
    dim3 big(1024);
    prep <<<dim3(16, 16, 3), blk, 0, stream>>>(x, W1, W2, b3, xhi, xlo,
                                               W1th, W1tl, W2th, W2tl, W2b, out);
    fwd1 <<<dim3(16, 16), big, 0, stream>>>(xhi, xlo, W1th, W1tl, b1, H1b, H1lo);
    fwd2 <<<dim3(16, 16), big, 0, stream>>>(H1b, H1lo, W2th, W2tl, b2, w3,
                                            H2b, G2b, out);
    g1k  <<<dim3(16, 16), big, 0, stream>>>(G2b, W2b, H1b, G1b);
    gramk<<<dim3(16, 16), big, 0, stream>>>(xhi, H1b, G1b, H2b, G2b, gram);
}